// Round 10
// baseline (196.696 us; speedup 1.0000x reference)
//
#include <hip/hip_runtime.h>
#include <cstdint>

typedef unsigned short u16;
typedef short v8s __attribute__((ext_vector_type(8)));
typedef float v4f __attribute__((ext_vector_type(4)));
typedef u16 u16x4 __attribute__((ext_vector_type(4)));

#define NB 2
#define NS 2048
#define ND 1024
#define NH 16
#define NM (NB * NS)   // 4096 tokens

__device__ __forceinline__ u16 f2bf(float f) {
  unsigned u = __float_as_uint(f);
  u += 0x7fff + ((u >> 16) & 1u);      // RNE
  return (u16)(u >> 16);
}
__device__ __forceinline__ float bf2f(u16 v) {
  return __uint_as_float(((unsigned)v) << 16);
}
// HW packed f32->bf16: D.lo = cvt(a), D.hi = cvt(b)
__device__ __forceinline__ unsigned pkbf(float a, float b) {
  unsigned r;
  asm("v_cvt_pk_bf16_f32 %0, %1, %2" : "=v"(r) : "v"(a), "v"(b));
  return r;
}
__device__ __forceinline__ void g2l16(const void* g, void* l) {
  __builtin_amdgcn_global_load_lds(
      (__attribute__((address_space(1))) void*)(void*)(uintptr_t)g,
      (__attribute__((address_space(3))) void*)l, 16, 0, 0);
}

// ---------------- prep: cast x -> bf16 + all weight transposes, one launch ----------------
__global__ void prep_kernel(const float* __restrict__ x, const float* __restrict__ wq,
                            const float* __restrict__ wkv, const float* __restrict__ wout,
                            u16* __restrict__ xb, u16* __restrict__ wqkvT, u16* __restrict__ woutT)
{
  int blk = blockIdx.x;
  if (blk >= 4096) {               // cast blocks: 2048 x 256 threads x 2 float4
    int i = (blk - 4096) * 256 + threadIdx.x;
    #pragma unroll
    for (int rep = 0; rep < 2; rep++) {
      int idx = i + rep * 524288;
      float4 v = ((const float4*)x)[idx];
      u16x4 o = { f2bf(v.x), f2bf(v.y), f2bf(v.z), f2bf(v.w) };
      ((u16x4*)xb)[idx] = o;
    }
    return;
  }
  __shared__ float tile[32][33];
  const float* W; u16* Wt; int N, bx, by;
  if (blk < 1024)      { W = wq;   Wt = wqkvT;                          N = 1024; bx = blk & 31;          by = blk >> 5; }
  else if (blk < 3072) { int b2 = blk - 1024; W = wkv; Wt = wqkvT + (size_t)1024 * 1024; N = 2048; bx = b2 & 63; by = b2 >> 6; }
  else                 { int b2 = blk - 3072; W = wout; Wt = woutT;     N = 1024; bx = b2 & 31;           by = b2 >> 5; }
  int n0 = bx * 32, k0 = by * 32;
  int tx = threadIdx.x & 31, ty = threadIdx.x >> 5;   // 32 x 8
  #pragma unroll
  for (int i = 0; i < 32; i += 8)
    tile[ty + i][tx] = W[(size_t)(k0 + ty + i) * N + n0 + tx];
  __syncthreads();
  #pragma unroll
  for (int i = 0; i < 32; i += 8)
    Wt[(size_t)(n0 + ty + i) * 1024 + k0 + tx] = f2bf(tile[tx][ty + i]);
}

// ---------------- qkv GEMM: 128x128 tile, fused l2-norm epilogue ----------------
__global__ __launch_bounds__(256, 2)
void gemm_qkv_kernel(const u16* __restrict__ A, const u16* __restrict__ Bt,
                     u16* __restrict__ qn, u16* __restrict__ kn, u16* __restrict__ vb,
                     const float* __restrict__ scale)
{
  __shared__ u16 As[128 * 64];
  __shared__ u16 Bs[128 * 64];
  const int tid = threadIdx.x;
  const int w = tid >> 6, l = tid & 63;
  const int m0 = blockIdx.y * 128, n0 = blockIdx.x * 128;
  const int wm = (w & 1) * 64, wn = (w >> 1) * 64;
  const int lr = l >> 3, lc = l & 7;
  const int lm = l & 15, g = l >> 4;
  v4f acc[4][4] = {};

  for (int kk = 0; kk < 1024; kk += 64) {
    #pragma unroll
    for (int i = 0; i < 4; i++) {
      int rb = w * 32 + i * 8;
      int r  = rb + lr;
      int c  = lc ^ (r & 7);
      g2l16(A  + (size_t)(m0 + r) * 1024 + kk + c * 8, &As[rb * 64]);
      g2l16(Bt + (size_t)(n0 + r) * 1024 + kk + c * 8, &Bs[rb * 64]);
    }
    __syncthreads();
    #pragma unroll
    for (int ks = 0; ks < 2; ks++) {
      v8s av[4], bv[4];
      #pragma unroll
      for (int i = 0; i < 4; i++) {
        int ra = wm + i * 16 + lm;
        int ca = (ks * 4 + g) ^ (ra & 7);
        av[i] = *(const v8s*)&As[ra * 64 + ca * 8];
        int rb2 = wn + i * 16 + lm;
        int cb = (ks * 4 + g) ^ (rb2 & 7);
        bv[i] = *(const v8s*)&Bs[rb2 * 64 + cb * 8];
      }
      #pragma unroll
      for (int mi = 0; mi < 4; mi++)
        #pragma unroll
        for (int ni = 0; ni < 4; ni++)
          acc[mi][ni] = __builtin_amdgcn_mfma_f32_16x16x32_bf16(av[mi], bv[ni], acc[mi][ni], 0, 0, 0);
    }
    __syncthreads();
  }

  // epilogue: C/D layout col = lane&15, row = (lane>>4)*4 + reg. 64-col block = one head.
  const int colBase = n0 + wn;
  const int sec = colBase >> 10;        // 0=q, 1=k, 2=v
  if (sec == 2) {
    const int vcol0 = colBase & 1023;
    #pragma unroll
    for (int mi = 0; mi < 4; mi++)
      #pragma unroll
      for (int ni = 0; ni < 4; ni++) {
        int row = m0 + wm + mi * 16 + g * 4;
        int col = vcol0 + ni * 16 + lm;
        #pragma unroll
        for (int r = 0; r < 4; r++)
          vb[(size_t)(row + r) * 1024 + col] = f2bf(acc[mi][ni][r]);
      }
  } else {
    const int h = (colBase >> 6) & 15;
    const float esc = (sec == 0) ? __expf(scale[h]) : 1.0f;
    u16* dst = (sec == 0) ? qn : kn;
    #pragma unroll
    for (int mi = 0; mi < 4; mi++) {
      #pragma unroll
      for (int r = 0; r < 4; r++) {
        float ss = 0.f;
        #pragma unroll
        for (int ni = 0; ni < 4; ni++) ss += acc[mi][ni][r] * acc[mi][ni][r];
        ss += __shfl_xor(ss, 1, 64); ss += __shfl_xor(ss, 2, 64);
        ss += __shfl_xor(ss, 4, 64); ss += __shfl_xor(ss, 8, 64);
        float f = esc * rsqrtf(fmaxf(ss, 1e-24f));
        int m = m0 + wm + mi * 16 + g * 4 + r;
        int b = m >> 11, s = m & (NS - 1);
        size_t base = (((size_t)(b * NH + h)) * NS + s) * 64;
        #pragma unroll
        for (int ni = 0; ni < 4; ni++)
          dst[base + ni * 16 + lm] = f2bf(acc[mi][ni][r] * f);
      }
    }
  }
}

// ---------------- out GEMM: 128x64 tile, single pass, fused bias, f32 out ----------------
__global__ __launch_bounds__(256, 2)
void gemm_out_kernel(const u16* __restrict__ A, const u16* __restrict__ Bt,
                     const float* __restrict__ bias, float* __restrict__ out)
{
  __shared__ u16 As[128 * 64];   // 16 KB
  __shared__ u16 Bs[64 * 64];    //  8 KB
  const int tid = threadIdx.x;
  const int w = tid >> 6, l = tid & 63;
  const int m0 = blockIdx.y * 128, n0 = blockIdx.x * 64;
  const int wm = w * 32;
  const int lr = l >> 3, lc = l & 7;
  const int lm = l & 15, g = l >> 4;
  v4f acc[2][4] = {};

  for (int kk = 0; kk < 1024; kk += 64) {
    #pragma unroll
    for (int i = 0; i < 4; i++) {
      int rb = w * 32 + i * 8;
      int r  = rb + lr;
      int c  = lc ^ (r & 7);
      g2l16(A + (size_t)(m0 + r) * 1024 + kk + c * 8, &As[rb * 64]);
    }
    #pragma unroll
    for (int i = 0; i < 2; i++) {
      int rb = w * 16 + i * 8;
      int r  = rb + lr;
      int c  = lc ^ (r & 7);
      g2l16(Bt + (size_t)(n0 + r) * 1024 + kk + c * 8, &Bs[rb * 64]);
    }
    __syncthreads();
    #pragma unroll
    for (int ks = 0; ks < 2; ks++) {
      v8s av[2], bv[4];
      #pragma unroll
      for (int mi = 0; mi < 2; mi++) {
        int ra = wm + mi * 16 + lm;
        int ca = (ks * 4 + g) ^ (ra & 7);
        av[mi] = *(const v8s*)&As[ra * 64 + ca * 8];
      }
      #pragma unroll
      for (int ni = 0; ni < 4; ni++) {
        int rb2 = ni * 16 + lm;
        int cb = (ks * 4 + g) ^ (rb2 & 7);
        bv[ni] = *(const v8s*)&Bs[rb2 * 64 + cb * 8];
      }
      #pragma unroll
      for (int mi = 0; mi < 2; mi++)
        #pragma unroll
        for (int ni = 0; ni < 4; ni++)
          acc[mi][ni] = __builtin_amdgcn_mfma_f32_16x16x32_bf16(av[mi], bv[ni], acc[mi][ni], 0, 0, 0);
    }
    __syncthreads();
  }

  #pragma unroll
  for (int mi = 0; mi < 2; mi++)
    #pragma unroll
    for (int ni = 0; ni < 4; ni++) {
      int row = m0 + wm + mi * 16 + g * 4;
      int col = n0 + ni * 16 + lm;
      float bb = bias[col];
      #pragma unroll
      for (int r = 0; r < 4; r++)
        out[(size_t)(row + r) * 1024 + col] = acc[mi][ni][r] + bb;
    }
}

// ---------------- pack V transposed: vt[b][h][d][s] = vb[b*NS+s][h*64+d] ----------------
__global__ void pack_vt_kernel(const u16* __restrict__ vb, u16* __restrict__ vt) {
  __shared__ u16 tile[64][65];
  int blk = blockIdx.x;
  int sc = blk & 31;              // S/64 chunks
  int bh = blk >> 5;
  int b = bh >> 4, h = bh & 15;
  int s0 = sc * 64;
  int x = threadIdx.x & 63, y4 = threadIdx.x >> 6;
  #pragma unroll
  for (int i = 0; i < 16; i++) {
    int s = i * 4 + y4;
    tile[s][x] = vb[(size_t)(b * NS + s0 + s) * 1024 + h * 64 + x];
  }
  __syncthreads();
  #pragma unroll
  for (int i = 0; i < 16; i++) {
    int d = i * 4 + y4;
    vt[((size_t)(bh * 64) + d) * NS + s0 + x] = tile[x][d];
  }
}

// ---------------- attention — green r9 structure scaled to 64 q/wave ----------------
// grid 1024; XCD swizzle: blk&7 = XCD, each XCD owns 4 whole bh (K+V slice 2MB < L2).
// 4 waves x 64 q-rows (mi=4: K/V frag reads amortize over 2x MFMA — LDS-pipe was the
// 70%-busy bottleneck at mi=2); j-split 4 -> 8 j-tiles of 64 per block. Ks single-
// buffered, Vs double-buffered (two barriers/tile). exp via 2-FMA poly. bf16 P via
// LDS (pitch-64 XOR swizzle). LDS 56KB -> 2 blocks/CU; VGPR ~190 -> 2 waves/SIMD.
__global__ __launch_bounds__(256, 2)
void attn_kernel(const u16* __restrict__ qn, const u16* __restrict__ kn,
                 const u16* __restrict__ vt, u16* __restrict__ num, float* __restrict__ den)
{
  __shared__ u16 Ks[64 * 64];        //  8 KB
  __shared__ u16 Vs[2][64 * 64];     // 16 KB
  __shared__ u16 Pb[4][4][16 * 64];  // 32 KB  -> 56 KB total
  const int tid = threadIdx.x;
  const int w = tid >> 6, l = tid & 63;
  const int lm = l & 15, g = l >> 4;
  const int xcd = blockIdx.x & 7;
  const int ii  = blockIdx.x >> 3;     // 0..127
  const int bh  = xcd * 4 + (ii >> 5);
  const int rem = ii & 31;
  const int p   = rem >> 3;            // 0..3 j-split
  const int qb  = rem & 7;             // 0..7 256-q block
  const int q0 = qb * 256 + w * 64;
  const int j0base = p * 512;          // 8 tiles of 64
  const u16* qk  = qn + (size_t)bh * NS * 64;
  const u16* kkp = kn + (size_t)bh * NS * 64;
  const u16* vv  = vt + (size_t)bh * 64 * NS;

  const int lr = l >> 3, lc = l & 7;

  v8s qf[4][2];
  #pragma unroll
  for (int mi = 0; mi < 4; mi++)
    #pragma unroll
    for (int ks = 0; ks < 2; ks++)
      qf[mi][ks] = *(const v8s*)&qk[(size_t)(q0 + mi * 16 + lm) * 64 + ks * 32 + g * 8];

  v4f oacc[4][4] = {};                 // [di][mi]
  float dsum[4] = {0.f, 0.f, 0.f, 0.f};

  // preload tile 0
  {
    #pragma unroll
    for (int i = 0; i < 2; i++) {
      int rb = w * 16 + i * 8;
      int r = rb + lr;
      int c = lc ^ (r & 7);
      g2l16(vv + (size_t)r * NS + j0base + c * 8, &Vs[0][rb * 64]);
      g2l16(kkp + (size_t)(j0base + r) * 64 + c * 8, &Ks[rb * 64]);
    }
  }

  for (int jt = 0; jt < 8; jt++) {
    const int cur = jt & 1;
    __syncthreads();                       // K[jt], V[jt] arrived; Vs[cur^1] free
    if (jt + 1 < 8) {
      int jb = j0base + (jt + 1) * 64;
      #pragma unroll
      for (int i = 0; i < 2; i++) {
        int rb = w * 16 + i * 8;
        int r = rb + lr;
        int c = lc ^ (r & 7);
        g2l16(vv + (size_t)r * NS + jb + c * 8, &Vs[cur ^ 1][rb * 64]);
      }
    }

    // ---- QK phase (reads Ks) ----
    v8s kf[4][2];
    #pragma unroll
    for (int ji = 0; ji < 4; ji++)
      #pragma unroll
      for (int ks = 0; ks < 2; ks++)
        kf[ji][ks] = *(const v8s*)&Ks[(ji * 16 + lm) * 64 + (((ks * 4 + g) ^ (lm & 7)) * 8)];
    #pragma unroll
    for (int mi = 0; mi < 4; mi++) {
      #pragma unroll
      for (int ji = 0; ji < 4; ji++) {
        v4f s = {0.f, 0.f, 0.f, 0.f};
        s = __builtin_amdgcn_mfma_f32_16x16x32_bf16(kf[ji][0], qf[mi][0], s, 0, 0, 0);
        s = __builtin_amdgcn_mfma_f32_16x16x32_bf16(kf[ji][1], qf[mi][1], s, 0, 0, 0);
        float pe[4];
        #pragma unroll
        for (int r = 0; r < 4; r++) {
          float sv = s[r];
          float t = __builtin_fmaf(sv, 0.5f, 1.0f);
          pe[r] = __builtin_fmaf(sv, t, 1.0f);        // exp(sv) to 1.6e-5
          dsum[mi] += pe[r];
        }
        int c = (ji * 4 + g) ^ ((lm & 7) << 1);
        uint2 pw = { pkbf(pe[0], pe[1]), pkbf(pe[2], pe[3]) };
        *(uint2*)&Pb[w][mi][lm * 64 + c * 4] = pw;
      }
    }

    __syncthreads();                       // all waves done reading Ks
    if (jt + 1 < 8) {
      int jb = j0base + (jt + 1) * 64;
      #pragma unroll
      for (int i = 0; i < 2; i++) {
        int rb = w * 16 + i * 8;
        int r = rb + lr;
        int c = lc ^ (r & 7);
        g2l16(kkp + (size_t)(jb + r) * 64 + c * 8, &Ks[rb * 64]);
      }
    }

    // ---- PV phase (reads Vs[cur] + own P) ----
    #pragma unroll
    for (int ks = 0; ks < 2; ks++) {
      v8s pf[4], vf[4];
      #pragma unroll
      for (int mi = 0; mi < 4; mi++) {
        int c0 = (ks * 8 + g * 2) ^ ((lm & 7) << 1);
        pf[mi] = *(const v8s*)&Pb[w][mi][lm * 64 + c0 * 4];
      }
      #pragma unroll
      for (int di = 0; di < 4; di++)
        vf[di] = *(const v8s*)&Vs[cur][(di * 16 + lm) * 64 + (((ks * 4 + g) ^ (lm & 7)) * 8)];
      #pragma unroll
      for (int di = 0; di < 4; di++)
        #pragma unroll
        for (int mi = 0; mi < 4; mi++)
          oacc[di][mi] = __builtin_amdgcn_mfma_f32_16x16x32_bf16(vf[di], pf[mi], oacc[di][mi], 0, 0, 0);
    }
  }

  // ---- partial epilogue: numerator bf16, denominator f32 ----
  #pragma unroll
  for (int mi = 0; mi < 4; mi++) {
    float d = dsum[mi];
    d += __shfl_xor(d, 16, 64);
    d += __shfl_xor(d, 32, 64);
    if (g == 0)
      den[(size_t)p * 65536 + (size_t)bh * NS + q0 + mi * 16 + lm] = d;
  }
  #pragma unroll
  for (int di = 0; di < 4; di++)
    #pragma unroll
    for (int mi = 0; mi < 4; mi++) {
      int q = q0 + mi * 16 + lm;
      uint2 o = { pkbf(oacc[di][mi][0], oacc[di][mi][1]),
                  pkbf(oacc[di][mi][2], oacc[di][mi][3]) };
      *(uint2*)&num[(size_t)p * 4194304 + ((size_t)bh * NS + q) * 64 + di * 16 + g * 4] = o;
    }
}

// ---------------- combine 4 attention partials -> ob (B,S,1024) bf16 ----------------
__global__ void attn_combine_kernel(const u16* __restrict__ num, const float* __restrict__ den,
                                    u16* __restrict__ ob)
{
  int t = blockIdx.x * 256 + threadIdx.x;      // 1,048,576 threads, 4 d each
  int d4 = t & 15;
  int q  = (t >> 4) & (NS - 1);
  int bh = t >> 15;
  int b = bh >> 4, h = bh & 15;
  size_t base = ((size_t)bh * NS + q) * 64 + d4 * 4;
  float dn = 0.f;
  float o0 = 0.f, o1 = 0.f, o2 = 0.f, o3 = 0.f;
  #pragma unroll
  for (int p = 0; p < 4; p++) {
    uint2 a = *(const uint2*)&num[(size_t)p * 4194304 + base];
    o0 += bf2f((u16)(a.x & 0xffff));
    o1 += bf2f((u16)(a.x >> 16));
    o2 += bf2f((u16)(a.y & 0xffff));
    o3 += bf2f((u16)(a.y >> 16));
    dn += den[(size_t)p * 65536 + (size_t)bh * NS + q];
  }
  float inv = 1.0f / dn;
  uint2 o = { pkbf(o0 * inv, o1 * inv), pkbf(o2 * inv, o3 * inv) };
  *(uint2*)&ob[((size_t)(b * NS + q)) * 1024 + h * 64 + d4 * 4] = o;
}

extern "C" void kernel_launch(void* const* d_in, const int* in_sizes, int n_in,
                              void* d_out, int out_size, void* d_ws, size_t ws_size,
                              hipStream_t stream)
{
  const float* x     = (const float*)d_in[0];
  const float* w_q   = (const float*)d_in[1];
  const float* w_kv  = (const float*)d_in[2];
  const float* w_out = (const float*)d_in[3];
  const float* b_out = (const float*)d_in[4];
  const float* scale = (const float*)d_in[5];

  // Workspace (MiB offsets), lifetimes non-overlapping:
  //   [0,2)   woutT   (prep .. out-gemm)
  //   [2,10)  xb      (prep .. qkv-gemm)  -> ob (attn_combine .. out-gemm)
  //   [10,16) wqkvT   (prep .. qkv-gemm)
  //   [16,24) vb      (qkv-gemm .. pack_vt)
  //   [10,42) num     (attn .. attn_combine)  [over dead wqkvT+vb; 4 partials x 8MB]
  //   [42,50) qn  [50,58) kn  [58,66) vt  [66,67) den (4 partials)
  char* ws = (char*)d_ws;
  u16*   woutT = (u16*)(ws);
  u16*   xb    = (u16*)(ws + (2ull  << 20));
  u16*   ob    = (u16*)(ws + (2ull  << 20));
  u16*   wqkvT = (u16*)(ws + (10ull << 20));
  u16*   numb  = (u16*)(ws + (10ull << 20));
  u16*   vb    = (u16*)(ws + (16ull << 20));
  u16*   qn    = (u16*)(ws + (42ull << 20));
  u16*   kn    = (u16*)(ws + (50ull << 20));
  u16*   vtb   = (u16*)(ws + (58ull << 20));
  float* denb  = (float*)(ws + (66ull << 20));

  prep_kernel<<<6144, 256, 0, stream>>>(x, w_q, w_kv, w_out, xb, wqkvT, woutT);
  gemm_qkv_kernel<<<dim3(24, 32), 256, 0, stream>>>(xb, wqkvT, qn, kn, vb, scale);
  pack_vt_kernel<<<1024, 256, 0, stream>>>(vb, vtb);
  attn_kernel<<<1024, 256, 0, stream>>>(qn, kn, vtb, numb, denb);
  attn_combine_kernel<<<4096, 256, 0, stream>>>(numb, denb, ob);
  gemm_out_kernel<<<dim3(16, 32), 256, 0, stream>>>(ob, woutT, b_out, (float*)d_out);
}